// Round 2
// baseline (1746.624 us; speedup 1.0000x reference)
//
#include <hip/hip_runtime.h>
#include <hip/hip_bf16.h>
#include <math.h>

// Problem constants (fixed by the reference)
#define BB 4
#define N_PER 50000
#define DEG 32
#define NUM_RELS 8
#define NUM_BASES 4
#define N_LAYERS 2
#define E_TOTAL (BB * N_PER * DEG)   // 6,400,000
#define N_TOTAL (BB * N_PER)         // 200,000
#define OUT_F 1024

// Workspace layout (floats):
//   [0..15]   relw (2 layers x 8 relations)
//   [16..19]  dot accumulator (4)
//   [32..]    agg1 (N_TOTAL), agg2 (N_TOTAL), x1 (N_TOTAL), x2 (N_TOTAL)

__global__ __launch_bounds__(256) void init_kernel(
    const float* __restrict__ feat1, const float* __restrict__ feat2,
    const float* __restrict__ bases, const float* __restrict__ w_comp,
    float* __restrict__ ws) {
  int tid = blockIdx.x * blockDim.x + threadIdx.x;
  if (blockIdx.x == 0) {
    if (threadIdx.x < 16) {
      int l = threadIdx.x >> 3, r = threadIdx.x & 7;
      float s = 0.f;
#pragma unroll
      for (int b = 0; b < NUM_BASES; ++b)
        s += w_comp[l * NUM_RELS * NUM_BASES + r * NUM_BASES + b] *
             bases[l * NUM_BASES + b];
      ws[l * 8 + r] = s;
    } else if (threadIdx.x < 20) {
      ws[16 + (threadIdx.x - 16)] = 0.f;  // dot accumulator
    }
  }
  float* agg1 = ws + 32;
  float* agg2 = agg1 + N_TOTAL;
  float* x1 = agg2 + N_TOTAL;
  float* x2 = x1 + N_TOTAL;
  for (int i = tid; i < N_TOTAL; i += gridDim.x * blockDim.x) {
    x1[i] = feat1[i];
    x2[i] = feat2[i];
    agg1[i] = 0.f;
    agg2[i] = 0.f;
  }
}

// 4 edges per thread; processes BOTH feature streams so edge data is read once.
__global__ __launch_bounds__(256) void edge_kernel(
    const int* __restrict__ src, const int* __restrict__ dst,
    const int* __restrict__ et, const float* __restrict__ norm,
    const float* __restrict__ ws, int layer,
    float* __restrict__ agg1, float* __restrict__ agg2,
    const float* __restrict__ x1, const float* __restrict__ x2) {
  __shared__ float w[NUM_RELS];
  if (threadIdx.x < NUM_RELS) w[threadIdx.x] = ws[layer * 8 + threadIdx.x];
  __syncthreads();
  int e = (blockIdx.x * blockDim.x + threadIdx.x) * 4;
  if (e >= E_TOTAL) return;
  int4 s4 = *(const int4*)(src + e);
  int4 d4 = *(const int4*)(dst + e);
  int4 t4 = *(const int4*)(et + e);
  float4 n4 = *(const float4*)(norm + e);
  {
    float c = w[t4.x] * n4.x;
    atomicAdd(&agg1[d4.x], x1[s4.x] * c);
    atomicAdd(&agg2[d4.x], x2[s4.x] * c);
  }
  {
    float c = w[t4.y] * n4.y;
    atomicAdd(&agg1[d4.y], x1[s4.y] * c);
    atomicAdd(&agg2[d4.y], x2[s4.y] * c);
  }
  {
    float c = w[t4.z] * n4.z;
    atomicAdd(&agg1[d4.z], x1[s4.z] * c);
    atomicAdd(&agg2[d4.z], x2[s4.z] * c);
  }
  {
    float c = w[t4.w] * n4.w;
    atomicAdd(&agg1[d4.w], x1[s4.w] * c);
    atomicAdd(&agg2[d4.w], x2[s4.w] * c);
  }
}

// h = agg + bias; relu (if not last layer); x = h + initial. Re-zeros agg.
__global__ __launch_bounds__(256) void node_kernel(
    const float* __restrict__ feat1, const float* __restrict__ feat2,
    const float* __restrict__ biases, int layer,
    float* __restrict__ agg1, float* __restrict__ agg2,
    float* __restrict__ x1, float* __restrict__ x2) {
  int i = blockIdx.x * blockDim.x + threadIdx.x;
  if (i >= N_TOTAL) return;
  float b = biases[layer];
  float h1 = agg1[i] + b;
  float h2 = agg2[i] + b;
  if (layer < N_LAYERS - 1) {
    h1 = fmaxf(h1, 0.f);
    h2 = fmaxf(h2, 0.f);
  }
  x1[i] = h1 + feat1[i];
  x2[i] = h2 + feat2[i];
  agg1[i] = 0.f;  // ready for next layer's edge pass
  agg2[i] = 0.f;
}

// One block per W_lin row j. Computes y1[i,j], y2[i,j] for i=0..3 and
// accumulates y1*y2 into acc[i] via atomics.
__global__ __launch_bounds__(256) void gemv_kernel(
    const float* __restrict__ W, const float* __restrict__ b_lin,
    const float* __restrict__ x1, const float* __restrict__ x2,
    float* __restrict__ acc) {
  int j = blockIdx.x;
  const float* wr = W + (size_t)j * N_PER;
  float a1[4] = {0.f, 0.f, 0.f, 0.f};
  float a2[4] = {0.f, 0.f, 0.f, 0.f};
  for (int k = threadIdx.x * 4; k <= N_PER - 4; k += 256 * 4) {
    float4 wv = *(const float4*)(wr + k);
#pragma unroll
    for (int i = 0; i < 4; ++i) {
      float4 v1 = *(const float4*)(x1 + i * N_PER + k);
      float4 v2 = *(const float4*)(x2 + i * N_PER + k);
      a1[i] += wv.x * v1.x + wv.y * v1.y + wv.z * v1.z + wv.w * v1.w;
      a2[i] += wv.x * v2.x + wv.y * v2.y + wv.z * v2.z + wv.w * v2.w;
    }
  }
#pragma unroll
  for (int off = 32; off > 0; off >>= 1) {
#pragma unroll
    for (int i = 0; i < 4; ++i) {
      a1[i] += __shfl_down(a1[i], off);
      a2[i] += __shfl_down(a2[i], off);
    }
  }
  __shared__ float red[4][8];
  int wave = threadIdx.x >> 6, lane = threadIdx.x & 63;
  if (lane == 0) {
#pragma unroll
    for (int i = 0; i < 4; ++i) {
      red[wave][i] = a1[i];
      red[wave][4 + i] = a2[i];
    }
  }
  __syncthreads();
  if (threadIdx.x == 0) {
    float bl = b_lin[j];
#pragma unroll
    for (int i = 0; i < 4; ++i) {
      float y1 = red[0][i] + red[1][i] + red[2][i] + red[3][i] + bl;
      float y2 = red[0][4 + i] + red[1][4 + i] + red[2][4 + i] + red[3][4 + i] + bl;
      atomicAdd(&acc[i], y1 * y2);
    }
  }
}

__global__ void sigmoid_kernel(const float* __restrict__ acc,
                               float* __restrict__ out) {
  int i = threadIdx.x;
  if (i < BB) out[i] = 1.f / (1.f + expf(-acc[i]));
}

extern "C" void kernel_launch(void* const* d_in, const int* in_sizes, int n_in,
                              void* d_out, int out_size, void* d_ws, size_t ws_size,
                              hipStream_t stream) {
  const float* feat1 = (const float*)d_in[0];
  const float* feat2 = (const float*)d_in[1];
  const int* src = (const int*)d_in[2];
  const int* dst = (const int*)d_in[3];
  const int* et = (const int*)d_in[4];
  const float* norm = (const float*)d_in[5];
  // d_in[6] = num_nodes (scalar) — constants hardcoded
  const float* bases = (const float*)d_in[7];
  const float* w_comp = (const float*)d_in[8];
  const float* biases = (const float*)d_in[9];
  const float* W_lin = (const float*)d_in[10];
  const float* b_lin = (const float*)d_in[11];
  float* out = (float*)d_out;

  float* ws = (float*)d_ws;
  float* relw = ws;
  float* acc = ws + 16;
  float* agg1 = ws + 32;
  float* agg2 = agg1 + N_TOTAL;
  float* x1 = agg2 + N_TOTAL;
  float* x2 = x1 + N_TOTAL;

  int nblk = (N_TOTAL + 255) / 256;
  init_kernel<<<nblk, 256, 0, stream>>>(feat1, feat2, bases, w_comp, ws);

  int eblk = (E_TOTAL / 4 + 255) / 256;  // 6250
  for (int l = 0; l < N_LAYERS; ++l) {
    edge_kernel<<<eblk, 256, 0, stream>>>(src, dst, et, norm, relw, l,
                                          agg1, agg2, x1, x2);
    node_kernel<<<nblk, 256, 0, stream>>>(feat1, feat2, biases, l,
                                          agg1, agg2, x1, x2);
  }

  gemv_kernel<<<OUT_F, 256, 0, stream>>>(W_lin, b_lin, x1, x2, acc);
  sigmoid_kernel<<<1, 64, 0, stream>>>(acc, out);
}

// Round 3
// 621.651 us; speedup vs baseline: 2.8097x; 2.8097x over previous
//
#include <hip/hip_runtime.h>
#include <hip/hip_bf16.h>
#include <math.h>

// Problem constants (fixed by the reference)
#define BB 4
#define N_PER 50000
#define DEG 32
#define NUM_RELS 8
#define NUM_BASES 4
#define N_LAYERS 2
#define E_PER (N_PER * DEG)          // 1,600,000 edges per graph
#define E_TOTAL (BB * E_PER)         // 6,400,000
#define N_TOTAL (BB * N_PER)         // 200,000
#define OUT_F 1024

// Destination-range binning (kills global atomics; LDS accumulate instead)
#define RANGES 4
#define RANGE_SZ (N_PER / RANGES)    // 12500 nodes -> 2 streams * 50KB = 100KB LDS
#define SUBS 16                      // edge-chunks per (graph,range)
#define EDGES_PER_BLOCK (E_PER / SUBS)      // 100000
#define GROUPS_PER_BLOCK (EDGES_PER_BLOCK / 4)  // 25000 float4-groups
#define PARTIAL_STRIDE (2 * RANGE_SZ)        // 25000 floats per block partial
#define NBLOCKS (BB * RANGES * SUBS)         // 256

// Workspace layout (floats):
//   [0..15]   relw (2 layers x 8 relations)
//   [16..19]  dot accumulator (4)
//   [32..]    x1 (N_TOTAL), x2 (N_TOTAL), partials (NBLOCKS * PARTIAL_STRIDE)

__global__ __launch_bounds__(256) void init_kernel(
    const float* __restrict__ feat1, const float* __restrict__ feat2,
    const float* __restrict__ bases, const float* __restrict__ w_comp,
    float* __restrict__ ws) {
  int tid = blockIdx.x * blockDim.x + threadIdx.x;
  if (blockIdx.x == 0) {
    if (threadIdx.x < 16) {
      int l = threadIdx.x >> 3, r = threadIdx.x & 7;
      float s = 0.f;
#pragma unroll
      for (int b = 0; b < NUM_BASES; ++b)
        s += w_comp[l * NUM_RELS * NUM_BASES + r * NUM_BASES + b] *
             bases[l * NUM_BASES + b];
      ws[l * 8 + r] = s;
    } else if (threadIdx.x < 20) {
      ws[16 + (threadIdx.x - 16)] = 0.f;  // dot accumulator
    }
  }
  float* x1 = ws + 32;
  float* x2 = x1 + N_TOTAL;
  for (int i = tid; i < N_TOTAL; i += gridDim.x * blockDim.x) {
    x1[i] = feat1[i];
    x2[i] = feat2[i];
  }
}

// One block = (graph b, dst-range r, edge-chunk sub). Accumulates both feature
// streams for its dst-range in LDS, then writes its partial bins with plain
// coalesced stores (NO global atomics).
__global__ __launch_bounds__(1024) void edge_bin_kernel(
    const int* __restrict__ src, const int* __restrict__ dst,
    const int* __restrict__ et, const float* __restrict__ norm,
    const float* __restrict__ relw, int layer,
    const float* __restrict__ x1, const float* __restrict__ x2,
    float* __restrict__ partials) {
  __shared__ float w[NUM_RELS];
  __shared__ float bin1[RANGE_SZ];
  __shared__ float bin2[RANGE_SZ];
  int bid = blockIdx.x;
  int sub = bid & (SUBS - 1);
  int br = bid >> 4;            // SUBS == 16
  int b = br >> 2, r = br & 3;  // RANGES == 4
  if (threadIdx.x < NUM_RELS) w[threadIdx.x] = relw[layer * 8 + threadIdx.x];
  for (int i = threadIdx.x; i < RANGE_SZ; i += blockDim.x) {
    bin1[i] = 0.f;
    bin2[i] = 0.f;
  }
  __syncthreads();

  int base = b * E_PER + sub * EDGES_PER_BLOCK;
  int node_lo = b * N_PER + r * RANGE_SZ;
  for (int g = threadIdx.x; g < GROUPS_PER_BLOCK; g += blockDim.x) {
    int e = base + g * 4;
    int4 s4 = *(const int4*)(src + e);
    int4 d4 = *(const int4*)(dst + e);
    int4 t4 = *(const int4*)(et + e);
    float4 n4 = *(const float4*)(norm + e);
    {
      int lr = d4.x - node_lo;
      if (lr >= 0 && lr < RANGE_SZ) {
        float c = w[t4.x] * n4.x;
        atomicAdd(&bin1[lr], x1[s4.x] * c);
        atomicAdd(&bin2[lr], x2[s4.x] * c);
      }
    }
    {
      int lr = d4.y - node_lo;
      if (lr >= 0 && lr < RANGE_SZ) {
        float c = w[t4.y] * n4.y;
        atomicAdd(&bin1[lr], x1[s4.y] * c);
        atomicAdd(&bin2[lr], x2[s4.y] * c);
      }
    }
    {
      int lr = d4.z - node_lo;
      if (lr >= 0 && lr < RANGE_SZ) {
        float c = w[t4.z] * n4.z;
        atomicAdd(&bin1[lr], x1[s4.z] * c);
        atomicAdd(&bin2[lr], x2[s4.z] * c);
      }
    }
    {
      int lr = d4.w - node_lo;
      if (lr >= 0 && lr < RANGE_SZ) {
        float c = w[t4.w] * n4.w;
        atomicAdd(&bin1[lr], x1[s4.w] * c);
        atomicAdd(&bin2[lr], x2[s4.w] * c);
      }
    }
  }
  __syncthreads();

  float* outp = partials + (size_t)bid * PARTIAL_STRIDE;
  for (int i = threadIdx.x; i < RANGE_SZ; i += blockDim.x) {
    outp[i] = bin1[i];
    outp[RANGE_SZ + i] = bin2[i];
  }
}

// Merge SUBS partials per (graph,range) + bias + ReLU(if layer0) + residual.
__global__ __launch_bounds__(256) void merge_node_kernel(
    const float* __restrict__ partials,
    const float* __restrict__ feat1, const float* __restrict__ feat2,
    const float* __restrict__ biases, int layer,
    float* __restrict__ x1, float* __restrict__ x2) {
  int i = blockIdx.x * 256 + threadIdx.x;
  if (i >= N_TOTAL) return;
  int b = i / N_PER;
  int local = i - b * N_PER;
  int r = local / RANGE_SZ;
  int lidx = local - r * RANGE_SZ;
  int blk0 = (b * RANGES + r) * SUBS;
  float s1 = 0.f, s2 = 0.f;
#pragma unroll
  for (int s = 0; s < SUBS; ++s) {
    const float* p = partials + (size_t)(blk0 + s) * PARTIAL_STRIDE;
    s1 += p[lidx];
    s2 += p[RANGE_SZ + lidx];
  }
  float bias = biases[layer];
  float h1 = s1 + bias, h2 = s2 + bias;
  if (layer < N_LAYERS - 1) {
    h1 = fmaxf(h1, 0.f);
    h2 = fmaxf(h2, 0.f);
  }
  x1[i] = h1 + feat1[i];
  x2[i] = h2 + feat2[i];
}

// One block per W_lin row j. Computes y1[i,j], y2[i,j] for i=0..3 and
// accumulates y1*y2 into acc[i] via atomics (4096 atomics total — negligible).
__global__ __launch_bounds__(256) void gemv_kernel(
    const float* __restrict__ W, const float* __restrict__ b_lin,
    const float* __restrict__ x1, const float* __restrict__ x2,
    float* __restrict__ acc) {
  int j = blockIdx.x;
  const float* wr = W + (size_t)j * N_PER;
  float a1[4] = {0.f, 0.f, 0.f, 0.f};
  float a2[4] = {0.f, 0.f, 0.f, 0.f};
  for (int k = threadIdx.x * 4; k <= N_PER - 4; k += 256 * 4) {
    float4 wv = *(const float4*)(wr + k);
#pragma unroll
    for (int i = 0; i < 4; ++i) {
      float4 v1 = *(const float4*)(x1 + i * N_PER + k);
      float4 v2 = *(const float4*)(x2 + i * N_PER + k);
      a1[i] += wv.x * v1.x + wv.y * v1.y + wv.z * v1.z + wv.w * v1.w;
      a2[i] += wv.x * v2.x + wv.y * v2.y + wv.z * v2.z + wv.w * v2.w;
    }
  }
#pragma unroll
  for (int off = 32; off > 0; off >>= 1) {
#pragma unroll
    for (int i = 0; i < 4; ++i) {
      a1[i] += __shfl_down(a1[i], off);
      a2[i] += __shfl_down(a2[i], off);
    }
  }
  __shared__ float red[4][8];
  int wave = threadIdx.x >> 6, lane = threadIdx.x & 63;
  if (lane == 0) {
#pragma unroll
    for (int i = 0; i < 4; ++i) {
      red[wave][i] = a1[i];
      red[wave][4 + i] = a2[i];
    }
  }
  __syncthreads();
  if (threadIdx.x == 0) {
    float bl = b_lin[j];
#pragma unroll
    for (int i = 0; i < 4; ++i) {
      float y1 = red[0][i] + red[1][i] + red[2][i] + red[3][i] + bl;
      float y2 = red[0][4 + i] + red[1][4 + i] + red[2][4 + i] + red[3][4 + i] + bl;
      atomicAdd(&acc[i], y1 * y2);
    }
  }
}

__global__ void sigmoid_kernel(const float* __restrict__ acc,
                               float* __restrict__ out) {
  int i = threadIdx.x;
  if (i < BB) out[i] = 1.f / (1.f + expf(-acc[i]));
}

extern "C" void kernel_launch(void* const* d_in, const int* in_sizes, int n_in,
                              void* d_out, int out_size, void* d_ws, size_t ws_size,
                              hipStream_t stream) {
  const float* feat1 = (const float*)d_in[0];
  const float* feat2 = (const float*)d_in[1];
  const int* src = (const int*)d_in[2];
  const int* dst = (const int*)d_in[3];
  const int* et = (const int*)d_in[4];
  const float* norm = (const float*)d_in[5];
  // d_in[6] = num_nodes (scalar) — constants hardcoded
  const float* bases = (const float*)d_in[7];
  const float* w_comp = (const float*)d_in[8];
  const float* biases = (const float*)d_in[9];
  const float* W_lin = (const float*)d_in[10];
  const float* b_lin = (const float*)d_in[11];
  float* out = (float*)d_out;

  float* ws = (float*)d_ws;
  float* relw = ws;
  float* acc = ws + 16;
  float* x1 = ws + 32;
  float* x2 = x1 + N_TOTAL;
  float* partials = x2 + N_TOTAL;  // NBLOCKS * PARTIAL_STRIDE floats = 25.6 MB

  int nblk = (N_TOTAL + 255) / 256;
  init_kernel<<<nblk, 256, 0, stream>>>(feat1, feat2, bases, w_comp, ws);

  for (int l = 0; l < N_LAYERS; ++l) {
    edge_bin_kernel<<<NBLOCKS, 1024, 0, stream>>>(src, dst, et, norm, relw, l,
                                                  x1, x2, partials);
    merge_node_kernel<<<nblk, 256, 0, stream>>>(partials, feat1, feat2, biases,
                                                l, x1, x2);
  }

  gemv_kernel<<<OUT_F, 256, 0, stream>>>(W_lin, b_lin, x1, x2, acc);
  sigmoid_kernel<<<1, 64, 0, stream>>>(acc, out);
}

// Round 5
// 554.910 us; speedup vs baseline: 3.1476x; 1.1203x over previous
//
#include <hip/hip_runtime.h>
#include <hip/hip_bf16.h>
#include <math.h>

// Problem constants (fixed by the reference)
#define BB 4
#define N_PER 50000
#define DEG 32
#define NUM_RELS 8
#define NUM_BASES 4
#define N_LAYERS 2
#define E_PER (N_PER * DEG)          // 1,600,000 edges per graph
#define E_TOTAL (BB * E_PER)         // 6,400,000
#define N_TOTAL (BB * N_PER)         // 200,000
#define OUT_F 1024

// Destination-range binning (LDS accumulate; no global atomics)
#define RANGES 4
#define RANGE_SZ (N_PER / RANGES)    // 12500 nodes -> 2 streams * 50KB = 100KB LDS
#define SUBS 16
#define EDGES_PER_BLOCK (E_PER / SUBS)          // 100000
#define GROUPS_PER_BLOCK (EDGES_PER_BLOCK / 4)  // 25000 float4-groups
#define PARTIAL_STRIDE (2 * RANGE_SZ)           // 25000 floats per block partial
#define NBLOCKS (BB * RANGES * SUBS)            // 256

// GEMV tiling: 8 rows/block, 10 k-splits of 5000 (5000*4B=20000B, 16B-aligned)
#define GR 8
#define GKSPLIT 10
#define GKCHUNK (N_PER / GKSPLIT)               // 5000
#define GROWBLKS (OUT_F / GR)                   // 128
#define GEMV_BLOCKS (GROWBLKS * GKSPLIT)        // 1280

// Workspace layout (floats):
//   [0..15]   relw (2 layers x 8 relations)
//   [16..31]  pad
//   [32..]    x1 (N_TOTAL), x2 (N_TOTAL),
//             partials (NBLOCKS*PARTIAL_STRIDE)  -- reused by gemv partials

__global__ __launch_bounds__(256) void init_kernel(
    const float* __restrict__ feat1, const float* __restrict__ feat2,
    const float* __restrict__ bases, const float* __restrict__ w_comp,
    float* __restrict__ ws) {
  int tid = blockIdx.x * blockDim.x + threadIdx.x;
  if (blockIdx.x == 0 && threadIdx.x < 16) {
    int l = threadIdx.x >> 3, r = threadIdx.x & 7;
    float s = 0.f;
#pragma unroll
    for (int b = 0; b < NUM_BASES; ++b)
      s += w_comp[l * NUM_RELS * NUM_BASES + r * NUM_BASES + b] *
           bases[l * NUM_BASES + b];
    ws[l * 8 + r] = s;
  }
  float* x1 = ws + 32;
  float* x2 = x1 + N_TOTAL;
  for (int i = tid; i < N_TOTAL; i += gridDim.x * blockDim.x) {
    x1[i] = feat1[i];
    x2[i] = feat2[i];
  }
}

// One block = (graph b, dst-range r, edge-chunk sub). LDS-accumulates both
// streams for its dst-range; writes partial bins with plain coalesced stores.
__global__ __launch_bounds__(1024) void edge_bin_kernel(
    const int* __restrict__ src, const int* __restrict__ dst,
    const int* __restrict__ et, const float* __restrict__ norm,
    const float* __restrict__ relw, int layer,
    const float* __restrict__ x1, const float* __restrict__ x2,
    float* __restrict__ partials) {
  __shared__ float w[NUM_RELS];
  __shared__ float bin1[RANGE_SZ];
  __shared__ float bin2[RANGE_SZ];
  int bid = blockIdx.x;
  int sub = bid & (SUBS - 1);
  int br = bid >> 4;            // SUBS == 16
  int b = br >> 2, r = br & 3;  // RANGES == 4
  if (threadIdx.x < NUM_RELS) w[threadIdx.x] = relw[layer * 8 + threadIdx.x];
  for (int i = threadIdx.x; i < RANGE_SZ; i += blockDim.x) {
    bin1[i] = 0.f;
    bin2[i] = 0.f;
  }
  __syncthreads();

  int base = b * E_PER + sub * EDGES_PER_BLOCK;
  int node_lo = b * N_PER + r * RANGE_SZ;
  for (int g = threadIdx.x; g < GROUPS_PER_BLOCK; g += blockDim.x) {
    int e = base + g * 4;
    int4 s4 = *(const int4*)(src + e);
    int4 d4 = *(const int4*)(dst + e);
    int4 t4 = *(const int4*)(et + e);
    float4 n4 = *(const float4*)(norm + e);
    {
      int lr = d4.x - node_lo;
      if (lr >= 0 && lr < RANGE_SZ) {
        float c = w[t4.x] * n4.x;
        atomicAdd(&bin1[lr], x1[s4.x] * c);
        atomicAdd(&bin2[lr], x2[s4.x] * c);
      }
    }
    {
      int lr = d4.y - node_lo;
      if (lr >= 0 && lr < RANGE_SZ) {
        float c = w[t4.y] * n4.y;
        atomicAdd(&bin1[lr], x1[s4.y] * c);
        atomicAdd(&bin2[lr], x2[s4.y] * c);
      }
    }
    {
      int lr = d4.z - node_lo;
      if (lr >= 0 && lr < RANGE_SZ) {
        float c = w[t4.z] * n4.z;
        atomicAdd(&bin1[lr], x1[s4.z] * c);
        atomicAdd(&bin2[lr], x2[s4.z] * c);
      }
    }
    {
      int lr = d4.w - node_lo;
      if (lr >= 0 && lr < RANGE_SZ) {
        float c = w[t4.w] * n4.w;
        atomicAdd(&bin1[lr], x1[s4.w] * c);
        atomicAdd(&bin2[lr], x2[s4.w] * c);
      }
    }
  }
  __syncthreads();

  float* outp = partials + (size_t)bid * PARTIAL_STRIDE;
  for (int i = threadIdx.x; i < RANGE_SZ; i += blockDim.x) {
    outp[i] = bin1[i];
    outp[RANGE_SZ + i] = bin2[i];
  }
}

// Merge SUBS partials per (graph,range) + bias + ReLU(if layer0) + residual.
__global__ __launch_bounds__(256) void merge_node_kernel(
    const float* __restrict__ partials,
    const float* __restrict__ feat1, const float* __restrict__ feat2,
    const float* __restrict__ biases, int layer,
    float* __restrict__ x1, float* __restrict__ x2) {
  int i = blockIdx.x * 256 + threadIdx.x;
  if (i >= N_TOTAL) return;
  int b = i / N_PER;
  int local = i - b * N_PER;
  int r = local / RANGE_SZ;
  int lidx = local - r * RANGE_SZ;
  int blk0 = (b * RANGES + r) * SUBS;
  float s1 = 0.f, s2 = 0.f;
#pragma unroll
  for (int s = 0; s < SUBS; ++s) {
    const float* p = partials + (size_t)(blk0 + s) * PARTIAL_STRIDE;
    s1 += p[lidx];
    s2 += p[RANGE_SZ + lidx];
  }
  float bias = biases[layer];
  float h1 = s1 + bias, h2 = s2 + bias;
  if (layer < N_LAYERS - 1) {
    h1 = fmaxf(h1, 0.f);
    h2 = fmaxf(h2, 0.f);
  }
  x1[i] = h1 + feat1[i];
  x2[i] = h2 + feat2[i];
}

// GEMV partial: block = (k-split ks, row-group rb). 8 W-rows x 5000-k chunk.
// Per k-step: 8 x-float4 loads are reused across 8 W-rows (64 accumulators).
__global__ __launch_bounds__(256) void gemv_part_kernel(
    const float* __restrict__ W,
    const float* __restrict__ x1, const float* __restrict__ x2,
    float* __restrict__ gpart) {
  int bid = blockIdx.x;
  int rb = bid & (GROWBLKS - 1);   // GROWBLKS == 128
  int ks = bid >> 7;
  int j0 = rb * GR;
  int k0 = ks * GKCHUNK;

  float acc[GR][8];
#pragma unroll
  for (int r = 0; r < GR; ++r)
#pragma unroll
    for (int g = 0; g < 8; ++g) acc[r][g] = 0.f;

  for (int k = k0 + threadIdx.x * 4; k < k0 + GKCHUNK; k += 256 * 4) {
    float4 xv[8];
#pragma unroll
    for (int i = 0; i < 4; ++i) {
      xv[2 * i] = *(const float4*)(x1 + i * N_PER + k);
      xv[2 * i + 1] = *(const float4*)(x2 + i * N_PER + k);
    }
#pragma unroll
    for (int r = 0; r < GR; ++r) {
      float4 wv = *(const float4*)(W + (size_t)(j0 + r) * N_PER + k);
#pragma unroll
      for (int g = 0; g < 8; ++g) {
        acc[r][g] += wv.x * xv[g].x + wv.y * xv[g].y +
                     wv.z * xv[g].z + wv.w * xv[g].w;
      }
    }
  }

  // wave reduce all 64 values
#pragma unroll
  for (int off = 32; off > 0; off >>= 1)
#pragma unroll
    for (int r = 0; r < GR; ++r)
#pragma unroll
      for (int g = 0; g < 8; ++g) acc[r][g] += __shfl_down(acc[r][g], off);

  __shared__ float red[4][GR * 8];
  int wave = threadIdx.x >> 6, lane = threadIdx.x & 63;
  if (lane == 0) {
#pragma unroll
    for (int r = 0; r < GR; ++r)
#pragma unroll
      for (int g = 0; g < 8; ++g) red[wave][r * 8 + g] = acc[r][g];
  }
  __syncthreads();
  if (threadIdx.x < GR * 8) {
    float s = red[0][threadIdx.x] + red[1][threadIdx.x] +
              red[2][threadIdx.x] + red[3][threadIdx.x];
    gpart[(size_t)bid * (GR * 8) + threadIdx.x] = s;
  }
}

// Final: thread j (row) sums k-splits, adds b_lin, forms y1*y2 per graph,
// block-reduces over 1024 rows, applies sigmoid. One block.
__global__ __launch_bounds__(1024) void gemv_reduce_kernel(
    const float* __restrict__ gpart, const float* __restrict__ b_lin,
    float* __restrict__ out) {
  int j = threadIdx.x;  // row 0..1023
  int rb = j >> 3, rr = j & 7;
  float y[8];
#pragma unroll
  for (int g = 0; g < 8; ++g) y[g] = 0.f;
#pragma unroll
  for (int ks = 0; ks < GKSPLIT; ++ks) {
    const float* p = gpart + (size_t)(ks * GROWBLKS + rb) * (GR * 8) + rr * 8;
#pragma unroll
    for (int g = 0; g < 8; ++g) y[g] += p[g];
  }
  float bl = b_lin[j];
  float prod[4];
#pragma unroll
  for (int i = 0; i < 4; ++i)
    prod[i] = (y[2 * i] + bl) * (y[2 * i + 1] + bl);

#pragma unroll
  for (int off = 32; off > 0; off >>= 1)
#pragma unroll
    for (int i = 0; i < 4; ++i) prod[i] += __shfl_down(prod[i], off);

  __shared__ float red[16][4];
  int wave = threadIdx.x >> 6, lane = threadIdx.x & 63;
  if (lane == 0) {
#pragma unroll
    for (int i = 0; i < 4; ++i) red[wave][i] = prod[i];
  }
  __syncthreads();
  if (threadIdx.x < 4) {
    float s = 0.f;
#pragma unroll
    for (int wv = 0; wv < 16; ++wv) s += red[wv][threadIdx.x];
    out[threadIdx.x] = 1.f / (1.f + expf(-s));
  }
}

extern "C" void kernel_launch(void* const* d_in, const int* in_sizes, int n_in,
                              void* d_out, int out_size, void* d_ws, size_t ws_size,
                              hipStream_t stream) {
  const float* feat1 = (const float*)d_in[0];
  const float* feat2 = (const float*)d_in[1];
  const int* src = (const int*)d_in[2];
  const int* dst = (const int*)d_in[3];
  const int* et = (const int*)d_in[4];
  const float* norm = (const float*)d_in[5];
  // d_in[6] = num_nodes (scalar) — constants hardcoded
  const float* bases = (const float*)d_in[7];
  const float* w_comp = (const float*)d_in[8];
  const float* biases = (const float*)d_in[9];
  const float* W_lin = (const float*)d_in[10];
  const float* b_lin = (const float*)d_in[11];
  float* out = (float*)d_out;

  float* ws = (float*)d_ws;
  float* relw = ws;
  float* x1 = ws + 32;
  float* x2 = x1 + N_TOTAL;
  float* partials = x2 + N_TOTAL;  // 25.6 MB; reused as gemv partials after

  int nblk = (N_TOTAL + 255) / 256;
  init_kernel<<<nblk, 256, 0, stream>>>(feat1, feat2, bases, w_comp, ws);

  for (int l = 0; l < N_LAYERS; ++l) {
    edge_bin_kernel<<<NBLOCKS, 1024, 0, stream>>>(src, dst, et, norm, relw, l,
                                                  x1, x2, partials);
    merge_node_kernel<<<nblk, 256, 0, stream>>>(partials, feat1, feat2, biases,
                                                l, x1, x2);
  }

  float* gpart = partials;  // edge partials are dead after last merge
  gemv_part_kernel<<<GEMV_BLOCKS, 256, 0, stream>>>(W_lin, x1, x2, gpart);
  gemv_reduce_kernel<<<1, 1024, 0, stream>>>(gpart, b_lin, out);
}

// Round 6
// 534.145 us; speedup vs baseline: 3.2699x; 1.0389x over previous
//
#include <hip/hip_runtime.h>
#include <hip/hip_bf16.h>
#include <math.h>

// Problem constants (fixed by the reference)
#define BB 4
#define N_PER 50000
#define DEG 32
#define NUM_RELS 8
#define NUM_BASES 4
#define N_LAYERS 2
#define E_PER (N_PER * DEG)          // 1,600,000 edges per graph
#define E_TOTAL (BB * E_PER)         // 6,400,000
#define N_TOTAL (BB * N_PER)         // 200,000
#define OUT_F 1024

// Destination-range binning (LDS accumulate; no global atomics)
#define RANGES 4
#define RANGE_SZ (N_PER / RANGES)    // 12500 nodes -> interleaved 100KB LDS
#define SUBS 16
#define EDGES_PER_BLOCK (E_PER / SUBS)          // 100000
#define GROUPS_PER_BLOCK (EDGES_PER_BLOCK / 4)  // 25000 float4-groups
#define PARTIAL_STRIDE (2 * RANGE_SZ)           // 25000 floats (float2/node)
#define NBLOCKS (BB * RANGES * SUBS)            // 256

// GEMV tiling: 8 rows/block, 10 k-splits of 5000
#define GR 8
#define GKSPLIT 10
#define GKCHUNK (N_PER / GKSPLIT)               // 5000
#define GROWBLKS (OUT_F / GR)                   // 128
#define GEMV_BLOCKS (GROWBLKS * GKSPLIT)        // 1280

// Workspace layout (floats):
//   [0..15]   relw (2 layers x 8 relations)
//   [16..31]  pad
//   [32..]    x12 (2*N_TOTAL, interleaved {x1,x2} per node),
//             partials (NBLOCKS*PARTIAL_STRIDE) -- reused as gemv partials

__global__ __launch_bounds__(256) void init_kernel(
    const float* __restrict__ feat1, const float* __restrict__ feat2,
    const float* __restrict__ bases, const float* __restrict__ w_comp,
    float* __restrict__ ws) {
  int tid = blockIdx.x * blockDim.x + threadIdx.x;
  if (blockIdx.x == 0 && threadIdx.x < 16) {
    int l = threadIdx.x >> 3, r = threadIdx.x & 7;
    float s = 0.f;
#pragma unroll
    for (int b = 0; b < NUM_BASES; ++b)
      s += w_comp[l * NUM_RELS * NUM_BASES + r * NUM_BASES + b] *
           bases[l * NUM_BASES + b];
    ws[l * 8 + r] = s;
  }
  float* x12 = ws + 32;
  for (int i = tid; i < N_TOTAL; i += gridDim.x * blockDim.x) {
    *(float2*)(x12 + 2 * (size_t)i) = make_float2(feat1[i], feat2[i]);
  }
}

// Block decode: bid = r*64 + (b*16 + sub). The 4 range-siblings of a
// (graph,chunk) pair are bid = pair + {0,64,128,192} == pair (mod 8) -> same
// XCD under round-robin dispatch, so the 1.6MB edge chunk is fetched into
// that XCD's L2 ONCE and shared (was 4 XCDs = 4x L2-fill traffic).
__global__ __launch_bounds__(1024) void edge_bin_kernel(
    const int* __restrict__ src, const int* __restrict__ dst,
    const int* __restrict__ et, const float* __restrict__ norm,
    const float* __restrict__ relw, int layer,
    const float* __restrict__ x12, float* __restrict__ partials) {
  __shared__ float w[NUM_RELS];
  __shared__ float bin[2 * RANGE_SZ];  // interleaved {s1,s2} per local node
  int bid = blockIdx.x;
  int r = bid >> 6;        // 0..3 (RANGES)
  int pair = bid & 63;
  int b = pair >> 4;       // 0..3 (BB)
  int sub = pair & 15;     // 0..15 (SUBS)
  if (threadIdx.x < NUM_RELS) w[threadIdx.x] = relw[layer * 8 + threadIdx.x];
  for (int i = threadIdx.x; i < 2 * RANGE_SZ; i += blockDim.x) bin[i] = 0.f;
  __syncthreads();

  int base = b * E_PER + sub * EDGES_PER_BLOCK;
  int node_lo = b * N_PER + r * RANGE_SZ;
  for (int g = threadIdx.x; g < GROUPS_PER_BLOCK; g += blockDim.x) {
    int e = base + g * 4;
    int4 s4 = *(const int4*)(src + e);
    int4 d4 = *(const int4*)(dst + e);
    int4 t4 = *(const int4*)(et + e);
    float4 n4 = *(const float4*)(norm + e);
    {
      int lr = d4.x - node_lo;
      if ((unsigned)lr < RANGE_SZ) {
        float2 xv = *(const float2*)(x12 + 2 * (size_t)s4.x);  // one 8B gather
        float c = w[t4.x] * n4.x;
        atomicAdd(&bin[2 * lr], xv.x * c);
        atomicAdd(&bin[2 * lr + 1], xv.y * c);
      }
    }
    {
      int lr = d4.y - node_lo;
      if ((unsigned)lr < RANGE_SZ) {
        float2 xv = *(const float2*)(x12 + 2 * (size_t)s4.y);
        float c = w[t4.y] * n4.y;
        atomicAdd(&bin[2 * lr], xv.x * c);
        atomicAdd(&bin[2 * lr + 1], xv.y * c);
      }
    }
    {
      int lr = d4.z - node_lo;
      if ((unsigned)lr < RANGE_SZ) {
        float2 xv = *(const float2*)(x12 + 2 * (size_t)s4.z);
        float c = w[t4.z] * n4.z;
        atomicAdd(&bin[2 * lr], xv.x * c);
        atomicAdd(&bin[2 * lr + 1], xv.y * c);
      }
    }
    {
      int lr = d4.w - node_lo;
      if ((unsigned)lr < RANGE_SZ) {
        float2 xv = *(const float2*)(x12 + 2 * (size_t)s4.w);
        float c = w[t4.w] * n4.w;
        atomicAdd(&bin[2 * lr], xv.x * c);
        atomicAdd(&bin[2 * lr + 1], xv.y * c);
      }
    }
  }
  __syncthreads();

  int idx = (b * RANGES + r) * SUBS + sub;  // partial slot (layout-stable)
  float* outp = partials + (size_t)idx * PARTIAL_STRIDE;
  for (int i = threadIdx.x; i < RANGE_SZ; i += blockDim.x) {
    // LDS read stride-2 (2-way aliasing = free); global store coalesced 8B
    *(float2*)(outp + 2 * i) = make_float2(bin[2 * i], bin[2 * i + 1]);
  }
}

// Merge SUBS partials per (graph,range) + bias + ReLU(if layer0) + residual.
__global__ __launch_bounds__(256) void merge_node_kernel(
    const float* __restrict__ partials,
    const float* __restrict__ feat1, const float* __restrict__ feat2,
    const float* __restrict__ biases, int layer, float* __restrict__ x12) {
  int i = blockIdx.x * 256 + threadIdx.x;
  if (i >= N_TOTAL) return;
  int b = i / N_PER;
  int local = i - b * N_PER;
  int r = local / RANGE_SZ;
  int lidx = local - r * RANGE_SZ;
  int blk0 = (b * RANGES + r) * SUBS;
  float s1 = 0.f, s2 = 0.f;
#pragma unroll
  for (int s = 0; s < SUBS; ++s) {
    float2 p = *(const float2*)(partials +
                                (size_t)(blk0 + s) * PARTIAL_STRIDE + 2 * lidx);
    s1 += p.x;
    s2 += p.y;
  }
  float bias = biases[layer];
  float h1 = s1 + bias, h2 = s2 + bias;
  if (layer < N_LAYERS - 1) {
    h1 = fmaxf(h1, 0.f);
    h2 = fmaxf(h2, 0.f);
  }
  *(float2*)(x12 + 2 * (size_t)i) = make_float2(h1 + feat1[i], h2 + feat2[i]);
}

// GEMV partial: block = (k-split ks, row-group rb). 8 W-rows x 5000-k chunk.
// x12 is interleaved: float4 at 2k = {x1[k],x2[k],x1[k+1],x2[k+1]}.
__global__ __launch_bounds__(256) void gemv_part_kernel(
    const float* __restrict__ W, const float* __restrict__ x12,
    float* __restrict__ gpart) {
  int bid = blockIdx.x;
  int rb = bid & (GROWBLKS - 1);   // GROWBLKS == 128
  int ks = bid >> 7;
  int j0 = rb * GR;
  int k0 = ks * GKCHUNK;

  float acc[GR][8];
#pragma unroll
  for (int r = 0; r < GR; ++r)
#pragma unroll
    for (int g = 0; g < 8; ++g) acc[r][g] = 0.f;

  for (int k = k0 + threadIdx.x * 4; k < k0 + GKCHUNK; k += 256 * 4) {
    float4 xa[4], xb[4];
#pragma unroll
    for (int i = 0; i < 4; ++i) {
      const float* xg = x12 + 2 * ((size_t)i * N_PER + k);
      xa[i] = *(const float4*)xg;        // k, k+1 (both streams)
      xb[i] = *(const float4*)(xg + 4);  // k+2, k+3
    }
#pragma unroll
    for (int r = 0; r < GR; ++r) {
      float4 wv = *(const float4*)(W + (size_t)(j0 + r) * N_PER + k);
#pragma unroll
      for (int i = 0; i < 4; ++i) {
        acc[r][2 * i] +=
            wv.x * xa[i].x + wv.y * xa[i].z + wv.z * xb[i].x + wv.w * xb[i].z;
        acc[r][2 * i + 1] +=
            wv.x * xa[i].y + wv.y * xa[i].w + wv.z * xb[i].y + wv.w * xb[i].w;
      }
    }
  }

#pragma unroll
  for (int off = 32; off > 0; off >>= 1)
#pragma unroll
    for (int r = 0; r < GR; ++r)
#pragma unroll
      for (int g = 0; g < 8; ++g) acc[r][g] += __shfl_down(acc[r][g], off);

  __shared__ float red[4][GR * 8];
  int wave = threadIdx.x >> 6, lane = threadIdx.x & 63;
  if (lane == 0) {
#pragma unroll
    for (int r = 0; r < GR; ++r)
#pragma unroll
      for (int g = 0; g < 8; ++g) red[wave][r * 8 + g] = acc[r][g];
  }
  __syncthreads();
  if (threadIdx.x < GR * 8) {
    float s = red[0][threadIdx.x] + red[1][threadIdx.x] +
              red[2][threadIdx.x] + red[3][threadIdx.x];
    gpart[(size_t)bid * (GR * 8) + threadIdx.x] = s;
  }
}

// Final: thread j (row) sums k-splits, adds b_lin, forms y1*y2 per graph,
// block-reduces over 1024 rows, applies sigmoid. One block.
__global__ __launch_bounds__(1024) void gemv_reduce_kernel(
    const float* __restrict__ gpart, const float* __restrict__ b_lin,
    float* __restrict__ out) {
  int j = threadIdx.x;  // row 0..1023
  int rb = j >> 3, rr = j & 7;
  float y[8];
#pragma unroll
  for (int g = 0; g < 8; ++g) y[g] = 0.f;
#pragma unroll
  for (int ks = 0; ks < GKSPLIT; ++ks) {
    const float* p = gpart + (size_t)(ks * GROWBLKS + rb) * (GR * 8) + rr * 8;
#pragma unroll
    for (int g = 0; g < 8; ++g) y[g] += p[g];
  }
  float bl = b_lin[j];
  float prod[4];
#pragma unroll
  for (int i = 0; i < 4; ++i)
    prod[i] = (y[2 * i] + bl) * (y[2 * i + 1] + bl);

#pragma unroll
  for (int off = 32; off > 0; off >>= 1)
#pragma unroll
    for (int i = 0; i < 4; ++i) prod[i] += __shfl_down(prod[i], off);

  __shared__ float red[16][4];
  int wave = threadIdx.x >> 6, lane = threadIdx.x & 63;
  if (lane == 0) {
#pragma unroll
    for (int i = 0; i < 4; ++i) red[wave][i] = prod[i];
  }
  __syncthreads();
  if (threadIdx.x < 4) {
    float s = 0.f;
#pragma unroll
    for (int wv = 0; wv < 16; ++wv) s += red[wv][threadIdx.x];
    out[threadIdx.x] = 1.f / (1.f + expf(-s));
  }
}

extern "C" void kernel_launch(void* const* d_in, const int* in_sizes, int n_in,
                              void* d_out, int out_size, void* d_ws, size_t ws_size,
                              hipStream_t stream) {
  const float* feat1 = (const float*)d_in[0];
  const float* feat2 = (const float*)d_in[1];
  const int* src = (const int*)d_in[2];
  const int* dst = (const int*)d_in[3];
  const int* et = (const int*)d_in[4];
  const float* norm = (const float*)d_in[5];
  // d_in[6] = num_nodes (scalar) — constants hardcoded
  const float* bases = (const float*)d_in[7];
  const float* w_comp = (const float*)d_in[8];
  const float* biases = (const float*)d_in[9];
  const float* W_lin = (const float*)d_in[10];
  const float* b_lin = (const float*)d_in[11];
  float* out = (float*)d_out;

  float* ws = (float*)d_ws;
  float* relw = ws;
  float* x12 = ws + 32;                 // 2*N_TOTAL floats, interleaved
  float* partials = x12 + 2 * N_TOTAL;  // 25.6 MB; reused as gemv partials

  int nblk = (N_TOTAL + 255) / 256;
  init_kernel<<<nblk, 256, 0, stream>>>(feat1, feat2, bases, w_comp, ws);

  for (int l = 0; l < N_LAYERS; ++l) {
    edge_bin_kernel<<<NBLOCKS, 1024, 0, stream>>>(src, dst, et, norm, relw, l,
                                                  x12, partials);
    merge_node_kernel<<<nblk, 256, 0, stream>>>(partials, feat1, feat2, biases,
                                                l, x12);
  }

  float* gpart = partials;  // edge partials are dead after last merge
  gemv_part_kernel<<<GEMV_BLOCKS, 256, 0, stream>>>(W_lin, x12, gpart);
  gemv_reduce_kernel<<<1, 1024, 0, stream>>>(gpart, b_lin, out);
}